// Round 11
// baseline (329.353 us; speedup 1.0000x reference)
//
#include <hip/hip_runtime.h>

// ScatterGeneralAttention, MI355X.
// R10: eliminate the rank buffer round-trip (4MB write + 4MB read): the
//      count kernel only counts; scatter regenerates each item's rank with a
//      second atomicAdd pass over a separately-zeroed counts2 (same L2-hot
//      atomic pattern, order-nondeterminism already present & within tol).
// R9 kept: no scan3 (split offsets off_p + bsums); NT idx load in scatter.
// R7 kept: seg_fused with NT loads/stores + 8-row software pipeline,
//      normalize-last streaming accumulate; cw merged into count kernel.
// R2/R1: V read once, counting-sort, no float atomics on rows, attn written
//      once. R0: probs = (v.(W^T a) + b.a) * D^-0.5; shift-invariant softmax.

#define DIM 256
#define WAVE 64

typedef float f4 __attribute__((ext_vector_type(4)));

// blocks 0..DIM: wc[k] = sum_j a[j]*W[j,k] (block DIM -> b.a);
// blocks DIM+1..: counts[idx[i]]++  (count only, no rank store)
__global__ void cw_count_kernel(const float* __restrict__ W,
                                const float* __restrict__ b,
                                const float* __restrict__ a,
                                float* __restrict__ wc,
                                const int* __restrict__ idx,
                                int* __restrict__ counts, int n) {
    const int t = threadIdx.x;
    if (blockIdx.x <= DIM) {
        const int k = blockIdx.x;
        __shared__ float sm[256];
        sm[t] = (k < DIM) ? a[t] * W[t * DIM + k] : a[t] * b[t];
        __syncthreads();
        for (int d = 128; d; d >>= 1) {
            if (t < d) sm[t] += sm[t + d];
            __syncthreads();
        }
        if (t == 0) wc[k] = sm[0];
    } else {
        const int i = (blockIdx.x - DIM - 1) * 256 + t;
        if (i < n) atomicAdd(&counts[idx[i]], 1);
    }
}

// Per-256-chunk exclusive scan (incl. sentinel position g==e); chunk sums out.
__global__ void scan1_kernel(const int* __restrict__ counts,
                             int* __restrict__ off_p,
                             int* __restrict__ bsums, int e) {
    __shared__ int s[256];
    const int t = threadIdx.x, g = blockIdx.x * 256 + t;
    const int x = (g < e) ? counts[g] : 0;
    s[t] = x; __syncthreads();
    for (int d = 1; d < 256; d <<= 1) {
        const int v = (t >= d) ? s[t - d] : 0; __syncthreads();
        s[t] += v; __syncthreads();
    }
    if (g <= e) off_p[g] = s[t] - x;           // within-chunk exclusive
    if (t == 255) bsums[blockIdx.x] = s[255];
}

// Exclusive scan of the <=512 chunk sums (1 block).
__global__ void scan2_kernel(int* __restrict__ bsums, int nb) {
    __shared__ int s[512];
    const int t = threadIdx.x;
    const int x = (t < nb) ? bsums[t] : 0;
    s[t] = x; __syncthreads();
    for (int d = 1; d < 512; d <<= 1) {
        const int v = (t >= d) ? s[t - d] : 0; __syncthreads();
        s[t] += v; __syncthreads();
    }
    if (t < nb) bsums[t] = s[t] - x;
}

// perm[off_p[seg] + bsums[seg>>8] + counts2[seg]++] = i
__global__ void scatter_kernel(const int* __restrict__ idx,
                               int* __restrict__ counts2,
                               const int* __restrict__ off_p,
                               const int* __restrict__ bsums,
                               int* __restrict__ perm, int n) {
    const int i = blockIdx.x * 256 + threadIdx.x;
    if (i < n) {
        const int seg = __builtin_nontemporal_load(idx + i);
        const int r   = atomicAdd(&counts2[seg], 1);
        perm[off_p[seg] + bsums[seg >> 8] + r] = i;
    }
}

// One wave per segment. Streaming normalize-last accumulate; chunks of 8 rows
// software-pipelined (prefetch next chunk); NT loads/stores on V/attn.
__global__ void seg_fused_kernel(const f4* __restrict__ v4,
                                 const int* __restrict__ perm,
                                 const float* __restrict__ wc,
                                 const int* __restrict__ off_p,
                                 const int* __restrict__ bsums,
                                 float* __restrict__ scores,
                                 float* __restrict__ attn, int e) {
    const int lane = threadIdx.x & (WAVE - 1);
    const int s = (blockIdx.x * blockDim.x + threadIdx.x) >> 6;
    if (s >= e) return;
    const f4 wf = ((const f4*)wc)[lane];
    const float c = wc[DIM];
    const int base = off_p[s] + bsums[s >> 8];
    const int cnt  = off_p[s + 1] + bsums[(s + 1) >> 8] - base;
    f4 acc = {0.f, 0.f, 0.f, 0.f};

    if (cnt > 0 && cnt <= WAVE) {               // covers all segs here (max~30)
        const int i_l = (lane < cnt) ? perm[base + lane] : 0;
        float myp = 0.f, d = 0.f;
        const int nch = (cnt + 7) >> 3;
        f4 cur[8], nxt[8];
        #pragma unroll
        for (int t = 0; t < 8; ++t)             // load chunk 0
            if (t < cnt)
                cur[t] = __builtin_nontemporal_load(
                    v4 + (size_t)__shfl(i_l, t, WAVE) * (DIM / 4) + lane);
        for (int ch = 0; ch < nch; ++ch) {
            const int st = ch * 8;
            if (ch + 1 < nch) {                 // prefetch chunk ch+1
                const int st2 = st + 8;
                #pragma unroll
                for (int t = 0; t < 8; ++t)
                    if (st2 + t < cnt)
                        nxt[t] = __builtin_nontemporal_load(
                            v4 + (size_t)__shfl(i_l, st2 + t, WAVE) * (DIM / 4) + lane);
            }
            #pragma unroll
            for (int t = 0; t < 8; ++t) {
                if (st + t < cnt) {
                    float pp = cur[t].x * wf.x + cur[t].y * wf.y
                             + cur[t].z * wf.z + cur[t].w * wf.w;
                    #pragma unroll
                    for (int off = 32; off; off >>= 1)
                        pp += __shfl_xor(pp, off, WAVE);
                    const float pe = __expf((pp + c) * 0.0625f);
                    d += pe;
                    acc.x += pe * cur[t].x; acc.y += pe * cur[t].y;
                    acc.z += pe * cur[t].z; acc.w += pe * cur[t].w;
                    if (lane == st + t) myp = pe;   // wave-uniform pe
                }
            }
            #pragma unroll
            for (int t = 0; t < 8; ++t) cur[t] = nxt[t];
        }
        const float inv = 1.f / d;
        if (lane < cnt) scores[i_l] = myp * inv;
        acc.x *= inv; acc.y *= inv; acc.z *= inv; acc.w *= inv;
    } else if (cnt > WAVE) {                    // correctness-only fallback
        float d = 0.f;
        for (int t = 0; t < cnt; ++t) {
            const int i = perm[base + t];
            const f4 vv = v4[(size_t)i * (DIM / 4) + lane];
            float pp = vv.x * wf.x + vv.y * wf.y + vv.z * wf.z + vv.w * wf.w;
            #pragma unroll
            for (int off = 32; off; off >>= 1) pp += __shfl_xor(pp, off, WAVE);
            const float pe = __expf((pp + c) * 0.0625f);
            d += pe;
            acc.x += pe * vv.x; acc.y += pe * vv.y;
            acc.z += pe * vv.z; acc.w += pe * vv.w;
        }
        const float inv = 1.f / d;
        for (int t = 0; t < cnt; ++t) {         // recompute scores, L2/L3-hot
            const int i = perm[base + t];
            const f4 vv = v4[(size_t)i * (DIM / 4) + lane];
            float pp = vv.x * wf.x + vv.y * wf.y + vv.z * wf.z + vv.w * wf.w;
            #pragma unroll
            for (int off = 32; off; off >>= 1) pp += __shfl_xor(pp, off, WAVE);
            if (lane == 0) scores[i] = __expf((pp + c) * 0.0625f) * inv;
        }
        acc.x *= inv; acc.y *= inv; acc.z *= inv; acc.w *= inv;
    }
    // attn row written exactly once, never re-read -> bypass L2 allocate
    __builtin_nontemporal_store(acc, (f4*)(attn + (size_t)s * DIM) + lane);
}

extern "C" void kernel_launch(void* const* d_in, const int* in_sizes, int n_in,
                              void* d_out, int out_size, void* d_ws, size_t ws_size,
                              hipStream_t stream) {
    const float* v   = (const float*)d_in[0];   // [N, 256]
    const int*   idx = (const int*)d_in[1];     // [N]
    const float* W   = (const float*)d_in[3];   // [256, 256]
    const float* b   = (const float*)d_in[4];   // [256]
    const float* a   = (const float*)d_in[5];   // [256]

    const int n = in_sizes[0] / DIM;            // 1,000,000
    const int e = (out_size - n) / DIM;         // 100,000
    const int nb = (e + 255) / 256;             // 391 <= 512

    float* scores = (float*)d_out;              // [N]
    float* attn   = (float*)d_out + n;          // [E, 256]

    // layout: wc(512f) | counts(E) | counts2(E) | off_p(E+2) | bsums(512) | perm(N)
    float* wc      = (float*)d_ws;
    int*   counts  = (int*)(wc + 512);          // [E]
    int*   counts2 = counts + e;                // [E]
    int*   off_p   = counts2 + e;               // [E+1] (+1 pad)
    int*   bsums   = off_p + e + 2;             // [<=512]
    int*   perm    = bsums + 512;               // [N]

    // one memset zeroes counts AND counts2 (adjacent)
    hipMemsetAsync(counts, 0, (size_t)(2 * e) * sizeof(int), stream);
    cw_count_kernel<<<DIM + 1 + (n + 255) / 256, 256, 0, stream>>>(
        W, b, a, wc, idx, counts, n);
    scan1_kernel<<<nb, 256, 0, stream>>>(counts, off_p, bsums, e);
    scan2_kernel<<<1, 512, 0, stream>>>(bsums, nb);
    scatter_kernel<<<(n + 255) / 256, 256, 0, stream>>>(idx, counts2, off_p,
                                                        bsums, perm, n);
    seg_fused_kernel<<<(e + 3) / 4, 256, 0, stream>>>((const f4*)v, perm, wc,
                                                      off_p, bsums,
                                                      scores, attn, e);
}

// Round 12
// 303.029 us; speedup vs baseline: 1.0869x; 1.0869x over previous
//
#include <hip/hip_runtime.h>

// ScatterGeneralAttention, MI355X.
// R11: revert R10's rank-regeneration (atomic-dependent perm store cost 40us;
//      rank round-trip restored). One change on R9: seg_fused is PERSISTENT
//      grid-stride over segments (8192 waves x ~12 segs) — block-retire
//      imbalance (E[max4 Poisson(10)]~14.5 vs mean 10) amortizes in-wave.
// R9 kept: no scan3 (split offsets off_p + bsums); NT idx/rank in scatter.
// R7 kept: seg_fused NT loads/stores + 8-row software pipeline,
//      normalize-last streaming accumulate; cw merged into rank kernel.
// R2/R1: V read once, counting-sort, no float atomics, attn written once.
// R0: probs = (v.(W^T a) + b.a) * D^-0.5; softmax shift-invariance.

#define DIM 256
#define WAVE 64

typedef float f4 __attribute__((ext_vector_type(4)));

// blocks 0..DIM: wc[k] = sum_j a[j]*W[j,k] (block DIM -> b.a);
// blocks DIM+1..: rank[i] = counts[idx[i]]++
__global__ void cw_rank_kernel(const float* __restrict__ W,
                               const float* __restrict__ b,
                               const float* __restrict__ a,
                               float* __restrict__ wc,
                               const int* __restrict__ idx,
                               int* __restrict__ counts,
                               int* __restrict__ rank, int n) {
    const int t = threadIdx.x;
    if (blockIdx.x <= DIM) {
        const int k = blockIdx.x;
        __shared__ float sm[256];
        sm[t] = (k < DIM) ? a[t] * W[t * DIM + k] : a[t] * b[t];
        __syncthreads();
        for (int d = 128; d; d >>= 1) {
            if (t < d) sm[t] += sm[t + d];
            __syncthreads();
        }
        if (t == 0) wc[k] = sm[0];
    } else {
        const int i = (blockIdx.x - DIM - 1) * 256 + t;
        if (i < n) rank[i] = atomicAdd(&counts[idx[i]], 1);
    }
}

// Per-256-chunk exclusive scan (incl. sentinel position g==e); chunk sums out.
__global__ void scan1_kernel(const int* __restrict__ counts,
                             int* __restrict__ off_p,
                             int* __restrict__ bsums, int e) {
    __shared__ int s[256];
    const int t = threadIdx.x, g = blockIdx.x * 256 + t;
    const int x = (g < e) ? counts[g] : 0;
    s[t] = x; __syncthreads();
    for (int d = 1; d < 256; d <<= 1) {
        const int v = (t >= d) ? s[t - d] : 0; __syncthreads();
        s[t] += v; __syncthreads();
    }
    if (g <= e) off_p[g] = s[t] - x;           // within-chunk exclusive
    if (t == 255) bsums[blockIdx.x] = s[255];
}

// Exclusive scan of the <=512 chunk sums (1 block).
__global__ void scan2_kernel(int* __restrict__ bsums, int nb) {
    __shared__ int s[512];
    const int t = threadIdx.x;
    const int x = (t < nb) ? bsums[t] : 0;
    s[t] = x; __syncthreads();
    for (int d = 1; d < 512; d <<= 1) {
        const int v = (t >= d) ? s[t - d] : 0; __syncthreads();
        s[t] += v; __syncthreads();
    }
    if (t < nb) bsums[t] = s[t] - x;
}

// perm[off_p[seg] + bsums[seg>>8] + rank[i]] = i  (ranks unique per segment)
__global__ void scatter_kernel(const int* __restrict__ idx,
                               const int* __restrict__ rank,
                               const int* __restrict__ off_p,
                               const int* __restrict__ bsums,
                               int* __restrict__ perm, int n) {
    const int i = blockIdx.x * 256 + threadIdx.x;
    if (i < n) {
        const int seg = __builtin_nontemporal_load(idx + i);
        const int r   = __builtin_nontemporal_load(rank + i);
        perm[off_p[seg] + bsums[seg >> 8] + r] = i;
    }
}

// Persistent waves, grid-stride over segments. Streaming normalize-last
// accumulate; 8-row software-pipelined chunks; NT loads/stores on V/attn.
__global__ void seg_fused_kernel(const f4* __restrict__ v4,
                                 const int* __restrict__ perm,
                                 const float* __restrict__ wc,
                                 const int* __restrict__ off_p,
                                 const int* __restrict__ bsums,
                                 float* __restrict__ scores,
                                 float* __restrict__ attn, int e) {
    const int lane = threadIdx.x & (WAVE - 1);
    const int gw = (blockIdx.x * blockDim.x + threadIdx.x) >> 6;
    const int nw = (gridDim.x * blockDim.x) >> 6;
    const f4 wf = ((const f4*)wc)[lane];
    const float c = wc[DIM];

    for (int s = gw; s < e; s += nw) {
        const int base = off_p[s] + bsums[s >> 8];
        const int cnt  = off_p[s + 1] + bsums[(s + 1) >> 8] - base;
        f4 acc = {0.f, 0.f, 0.f, 0.f};

        if (cnt > 0 && cnt <= WAVE) {           // covers all segs here (max~30)
            const int i_l = (lane < cnt) ? perm[base + lane] : 0;
            float myp = 0.f, d = 0.f;
            const int nch = (cnt + 7) >> 3;
            f4 cur[8], nxt[8];
            #pragma unroll
            for (int t = 0; t < 8; ++t)         // load chunk 0
                if (t < cnt)
                    cur[t] = __builtin_nontemporal_load(
                        v4 + (size_t)__shfl(i_l, t, WAVE) * (DIM / 4) + lane);
            for (int ch = 0; ch < nch; ++ch) {
                const int st = ch * 8;
                if (ch + 1 < nch) {             // prefetch chunk ch+1
                    const int st2 = st + 8;
                    #pragma unroll
                    for (int t = 0; t < 8; ++t)
                        if (st2 + t < cnt)
                            nxt[t] = __builtin_nontemporal_load(
                                v4 + (size_t)__shfl(i_l, st2 + t, WAVE) * (DIM / 4) + lane);
                }
                #pragma unroll
                for (int t = 0; t < 8; ++t) {
                    if (st + t < cnt) {
                        float pp = cur[t].x * wf.x + cur[t].y * wf.y
                                 + cur[t].z * wf.z + cur[t].w * wf.w;
                        #pragma unroll
                        for (int off = 32; off; off >>= 1)
                            pp += __shfl_xor(pp, off, WAVE);
                        const float pe = __expf((pp + c) * 0.0625f);
                        d += pe;
                        acc.x += pe * cur[t].x; acc.y += pe * cur[t].y;
                        acc.z += pe * cur[t].z; acc.w += pe * cur[t].w;
                        if (lane == st + t) myp = pe;   // wave-uniform pe
                    }
                }
                #pragma unroll
                for (int t = 0; t < 8; ++t) cur[t] = nxt[t];
            }
            const float inv = 1.f / d;
            if (lane < cnt) scores[i_l] = myp * inv;
            acc.x *= inv; acc.y *= inv; acc.z *= inv; acc.w *= inv;
        } else if (cnt > WAVE) {                // correctness-only fallback
            float d = 0.f;
            for (int t = 0; t < cnt; ++t) {
                const int i = perm[base + t];
                const f4 vv = v4[(size_t)i * (DIM / 4) + lane];
                float pp = vv.x * wf.x + vv.y * wf.y + vv.z * wf.z + vv.w * wf.w;
                #pragma unroll
                for (int off = 32; off; off >>= 1) pp += __shfl_xor(pp, off, WAVE);
                const float pe = __expf((pp + c) * 0.0625f);
                d += pe;
                acc.x += pe * vv.x; acc.y += pe * vv.y;
                acc.z += pe * vv.z; acc.w += pe * vv.w;
            }
            const float inv = 1.f / d;
            for (int t = 0; t < cnt; ++t) {     // recompute scores, L2/L3-hot
                const int i = perm[base + t];
                const f4 vv = v4[(size_t)i * (DIM / 4) + lane];
                float pp = vv.x * wf.x + vv.y * wf.y + vv.z * wf.z + vv.w * wf.w;
                #pragma unroll
                for (int off = 32; off; off >>= 1) pp += __shfl_xor(pp, off, WAVE);
                if (lane == 0) scores[i] = __expf((pp + c) * 0.0625f) * inv;
            }
            acc.x *= inv; acc.y *= inv; acc.z *= inv; acc.w *= inv;
        }
        // attn row written exactly once, never re-read -> bypass L2 allocate
        __builtin_nontemporal_store(acc, (f4*)(attn + (size_t)s * DIM) + lane);
    }
}

extern "C" void kernel_launch(void* const* d_in, const int* in_sizes, int n_in,
                              void* d_out, int out_size, void* d_ws, size_t ws_size,
                              hipStream_t stream) {
    const float* v   = (const float*)d_in[0];   // [N, 256]
    const int*   idx = (const int*)d_in[1];     // [N]
    const float* W   = (const float*)d_in[3];   // [256, 256]
    const float* b   = (const float*)d_in[4];   // [256]
    const float* a   = (const float*)d_in[5];   // [256]

    const int n = in_sizes[0] / DIM;            // 1,000,000
    const int e = (out_size - n) / DIM;         // 100,000
    const int nb = (e + 255) / 256;             // 391 <= 512

    float* scores = (float*)d_out;              // [N]
    float* attn   = (float*)d_out + n;          // [E, 256]

    // layout: wc(512f) | counts(E) | off_p(E+2) | bsums(512) | rank(N) | perm(N)
    float* wc     = (float*)d_ws;
    int*   counts = (int*)(wc + 512);           // [E]
    int*   off_p  = counts + e;                 // [E+1] (+1 pad)
    int*   bsums  = off_p + e + 2;              // [<=512]
    int*   rank   = bsums + 512;                // [N]
    int*   perm   = rank + n;                   // [N]

    hipMemsetAsync(counts, 0, (size_t)e * sizeof(int), stream);
    cw_rank_kernel<<<DIM + 1 + (n + 255) / 256, 256, 0, stream>>>(
        W, b, a, wc, idx, counts, rank, n);
    scan1_kernel<<<nb, 256, 0, stream>>>(counts, off_p, bsums, e);
    scan2_kernel<<<1, 512, 0, stream>>>(bsums, nb);
    scatter_kernel<<<(n + 255) / 256, 256, 0, stream>>>(idx, rank, off_p, bsums,
                                                        perm, n);
    seg_fused_kernel<<<2048, 256, 0, stream>>>((const f4*)v, perm, wc,
                                               off_p, bsums, scores, attn, e);
}

// Round 13
// 283.903 us; speedup vs baseline: 1.1601x; 1.0674x over previous
//
#include <hip/hip_runtime.h>

// ScatterGeneralAttention, MI355X.
// R12: revert to the best-known configuration (R7, 284us). R8 lookback
//      (+95us), R10 rank-regen (+45us), R11 persistent waves (+16us) all
//      regressed and are reverted. This IS the R7 kernel verbatim.
// Structure: probs = (v.(W^T a) + b.a) * D^-0.5 (GEMM collapsed away);
//      counting-sort by segment (rank -> scan x3 -> scatter perm);
//      seg_fused: one wave per segment, V read ONCE via NT loads, 8-row
//      software-pipelined chunks, normalize-last streaming accumulate,
//      attn row written exactly once via NT store. No float atomics.

#define DIM 256
#define WAVE 64

typedef float f4 __attribute__((ext_vector_type(4)));

// blocks 0..DIM: wc[k] = sum_j a[j]*W[j,k] (block DIM -> b.a);
// blocks DIM+1..: rank[i] = counts[idx[i]]++
__global__ void cw_rank_kernel(const float* __restrict__ W,
                               const float* __restrict__ b,
                               const float* __restrict__ a,
                               float* __restrict__ wc,
                               const int* __restrict__ idx,
                               int* __restrict__ counts,
                               int* __restrict__ rank, int n) {
    const int t = threadIdx.x;
    if (blockIdx.x <= DIM) {
        const int k = blockIdx.x;
        __shared__ float sm[256];
        sm[t] = (k < DIM) ? a[t] * W[t * DIM + k] : a[t] * b[t];
        __syncthreads();
        for (int d = 128; d; d >>= 1) {
            if (t < d) sm[t] += sm[t + d];
            __syncthreads();
        }
        if (t == 0) wc[k] = sm[0];
    } else {
        const int i = (blockIdx.x - DIM - 1) * 256 + t;
        if (i < n) rank[i] = atomicAdd(&counts[idx[i]], 1);
    }
}

// Hierarchical exclusive scan over counts[0..e) -> offsets (offsets[e]=n).
// Assumes ceil(e/256) <= 512 (e <= 131072; here e = 100000).
__global__ void scan1_kernel(const int* __restrict__ counts,
                             int* __restrict__ offsets,
                             int* __restrict__ bsums, int e) {
    __shared__ int s[256];
    const int t = threadIdx.x, g = blockIdx.x * 256 + t;
    const int x = (g < e) ? counts[g] : 0;
    s[t] = x; __syncthreads();
    for (int d = 1; d < 256; d <<= 1) {
        const int v = (t >= d) ? s[t - d] : 0; __syncthreads();
        s[t] += v; __syncthreads();
    }
    if (g < e) offsets[g] = s[t] - x;
    if (t == 255) bsums[blockIdx.x] = s[255];
}

__global__ void scan2_kernel(int* __restrict__ bsums, int nb) {
    __shared__ int s[512];
    const int t = threadIdx.x;
    const int x = (t < nb) ? bsums[t] : 0;
    s[t] = x; __syncthreads();
    for (int d = 1; d < 512; d <<= 1) {
        const int v = (t >= d) ? s[t - d] : 0; __syncthreads();
        s[t] += v; __syncthreads();
    }
    if (t < nb) bsums[t] = s[t] - x;
}

__global__ void scan3_kernel(int* __restrict__ offsets,
                             const int* __restrict__ bsums, int e, int n) {
    const int g = blockIdx.x * 256 + threadIdx.x;
    if (g < e) offsets[g] += bsums[blockIdx.x];
    if (g == 0) offsets[e] = n;
}

// perm[offsets[seg] + rank[i]] = i   (no atomics; ranks unique per segment)
__global__ void scatter_kernel(const int* __restrict__ idx,
                               const int* __restrict__ rank,
                               const int* __restrict__ offsets,
                               int* __restrict__ perm, int n) {
    const int i = blockIdx.x * 256 + threadIdx.x;
    if (i < n) perm[offsets[idx[i]] + rank[i]] = i;
}

// One wave per segment. Streaming normalize-last accumulate; chunks of 8 rows
// software-pipelined (prefetch next chunk); NT loads/stores on V/attn.
__global__ void seg_fused_kernel(const f4* __restrict__ v4,
                                 const int* __restrict__ perm,
                                 const float* __restrict__ wc,
                                 const int* __restrict__ offsets,
                                 float* __restrict__ scores,
                                 float* __restrict__ attn, int e) {
    const int lane = threadIdx.x & (WAVE - 1);
    const int s = (blockIdx.x * blockDim.x + threadIdx.x) >> 6;
    if (s >= e) return;
    const f4 wf = ((const f4*)wc)[lane];
    const float c = wc[DIM];
    const int base = offsets[s];
    const int cnt  = offsets[s + 1] - base;
    f4 acc = {0.f, 0.f, 0.f, 0.f};

    if (cnt > 0 && cnt <= WAVE) {               // covers all segs here (max~30)
        const int i_l = (lane < cnt) ? perm[base + lane] : 0;
        float myp = 0.f, d = 0.f;
        const int nch = (cnt + 7) >> 3;
        f4 cur[8], nxt[8];
        #pragma unroll
        for (int t = 0; t < 8; ++t)             // load chunk 0
            if (t < cnt)
                cur[t] = __builtin_nontemporal_load(
                    v4 + (size_t)__shfl(i_l, t, WAVE) * (DIM / 4) + lane);
        for (int ch = 0; ch < nch; ++ch) {
            const int st = ch * 8;
            if (ch + 1 < nch) {                 // prefetch chunk ch+1
                const int st2 = st + 8;
                #pragma unroll
                for (int t = 0; t < 8; ++t)
                    if (st2 + t < cnt)
                        nxt[t] = __builtin_nontemporal_load(
                            v4 + (size_t)__shfl(i_l, st2 + t, WAVE) * (DIM / 4) + lane);
            }
            #pragma unroll
            for (int t = 0; t < 8; ++t) {
                if (st + t < cnt) {
                    float pp = cur[t].x * wf.x + cur[t].y * wf.y
                             + cur[t].z * wf.z + cur[t].w * wf.w;
                    #pragma unroll
                    for (int off = 32; off; off >>= 1)
                        pp += __shfl_xor(pp, off, WAVE);
                    const float pe = __expf((pp + c) * 0.0625f);
                    d += pe;
                    acc.x += pe * cur[t].x; acc.y += pe * cur[t].y;
                    acc.z += pe * cur[t].z; acc.w += pe * cur[t].w;
                    if (lane == st + t) myp = pe;   // wave-uniform pe
                }
            }
            #pragma unroll
            for (int t = 0; t < 8; ++t) cur[t] = nxt[t];
        }
        const float inv = 1.f / d;
        if (lane < cnt) scores[i_l] = myp * inv;
        acc.x *= inv; acc.y *= inv; acc.z *= inv; acc.w *= inv;
    } else if (cnt > WAVE) {                    // correctness-only fallback
        float d = 0.f;
        for (int t = 0; t < cnt; ++t) {
            const int i = perm[base + t];
            const f4 vv = v4[(size_t)i * (DIM / 4) + lane];
            float pp = vv.x * wf.x + vv.y * wf.y + vv.z * wf.z + vv.w * wf.w;
            #pragma unroll
            for (int off = 32; off; off >>= 1) pp += __shfl_xor(pp, off, WAVE);
            const float pe = __expf((pp + c) * 0.0625f);
            d += pe;
            acc.x += pe * vv.x; acc.y += pe * vv.y;
            acc.z += pe * vv.z; acc.w += pe * vv.w;
        }
        const float inv = 1.f / d;
        for (int t = 0; t < cnt; ++t) {         // recompute scores, L2/L3-hot
            const int i = perm[base + t];
            const f4 vv = v4[(size_t)i * (DIM / 4) + lane];
            float pp = vv.x * wf.x + vv.y * wf.y + vv.z * wf.z + vv.w * wf.w;
            #pragma unroll
            for (int off = 32; off; off >>= 1) pp += __shfl_xor(pp, off, WAVE);
            if (lane == 0) scores[i] = __expf((pp + c) * 0.0625f) * inv;
        }
        acc.x *= inv; acc.y *= inv; acc.z *= inv; acc.w *= inv;
    }
    // attn row written exactly once, never re-read -> bypass L2 allocate
    __builtin_nontemporal_store(acc, (f4*)(attn + (size_t)s * DIM) + lane);
}

extern "C" void kernel_launch(void* const* d_in, const int* in_sizes, int n_in,
                              void* d_out, int out_size, void* d_ws, size_t ws_size,
                              hipStream_t stream) {
    const float* v   = (const float*)d_in[0];   // [N, 256]
    const int*   idx = (const int*)d_in[1];     // [N]
    const float* W   = (const float*)d_in[3];   // [256, 256]
    const float* b   = (const float*)d_in[4];   // [256]
    const float* a   = (const float*)d_in[5];   // [256]

    const int n = in_sizes[0] / DIM;            // 1,000,000
    const int e = (out_size - n) / DIM;         // 100,000
    const int nb = (e + 255) / 256;             // 391 <= 512

    float* scores = (float*)d_out;              // [N]
    float* attn   = (float*)d_out + n;          // [E, 256]

    // layout: wc(512f) | counts(E) | offsets(E+2) | bsums(512) | rank(N) | perm(N)
    float* wc      = (float*)d_ws;
    int*   counts  = (int*)(wc + 512);          // [E]
    int*   offsets = counts + e;                // [E+1] (+1 pad)
    int*   bsums   = offsets + e + 2;           // [<=512]
    int*   rank    = bsums + 512;               // [N]
    int*   perm    = rank + n;                  // [N]

    hipMemsetAsync(counts, 0, (size_t)e * sizeof(int), stream);
    cw_rank_kernel<<<DIM + 1 + (n + 255) / 256, 256, 0, stream>>>(
        W, b, a, wc, idx, counts, rank, n);
    scan1_kernel<<<nb, 256, 0, stream>>>(counts, offsets, bsums, e);
    scan2_kernel<<<1, 512, 0, stream>>>(bsums, nb);
    scan3_kernel<<<nb, 256, 0, stream>>>(offsets, bsums, e, n);
    scatter_kernel<<<(n + 255) / 256, 256, 0, stream>>>(idx, rank, offsets, perm, n);

    seg_fused_kernel<<<(e + 3) / 4, 256, 0, stream>>>((const f4*)v, perm, wc,
                                                      offsets, scores, attn, e);
}